// Round 4
// baseline (739.437 us; speedup 1.0000x reference)
//
#include <hip/hip_runtime.h>
#include <cstdint>
#include <math.h>

#pragma clang fp contract(off)

typedef unsigned int u32;
typedef unsigned long long u64;

#define HFEAT 512
#define WFEAT 512
#define NPIX (HFEAT*WFEAT)          // 262144
#define TOPK 4000
#define IMG_SZ 16384.0f
#define NBUCKET 8192
#define CAP 32768

// ---- workspace layout (bytes) ----
#define WS_HIST 0                    // u32[8192]   32768
#define WS_META 32768                // u32[16]     64
#define WS_CKEY 32832                // u32[CAP]    131072
#define WS_CIDX 163904               // u32[CAP]    131072
#define WS_SEL  294976               // u32[TOPK]   16000
#define WS_NX1  310976               // f32[TOPK]
#define WS_NY1  326976
#define WS_NX2  342976
#define WS_NY2  358976
#define WS_NAR  374976
#define WS_VAL  390976               // u32[TOPK] -> 406976
#define WS_MASK 409600               // u64[4000*64] = 2,048,000 -> 2,457,600
#define WS_DIAG (WS_MASK + (size_t)TOPK*64*8)        // u64[4000] = 32,000
#define WS_END_FAST (WS_DIAG + (size_t)TOPK*8)       // 2,489,600

// f32 softmax over 2 logits, replicating numpy float32 op-for-op.
__device__ __forceinline__ void softmax2(float l0, float l1, float& s0, float& s1) {
    float m = fmaxf(l0, l1);
    float a0 = l0 - m;
    float a1 = l1 - m;
    float e0 = (float)::exp((double)a0);
    float e1 = (float)::exp((double)a1);
    float den = e0 + e1;
    s0 = e0 / den;
    s1 = e1 / den;
}

__global__ void k_zero(u32* ws32) {
    int t = blockIdx.x * blockDim.x + threadIdx.x;
    if (t < NBUCKET + 16) ws32[t] = 0;
}

// histogram of f32 score bits for score > 0.5; bucket = (bits - 0x3F000000) >> 10
__global__ void k_hist(const float* __restrict__ obj, u32* __restrict__ hist) {
    __shared__ u32 lh[NBUCKET];
    int tid = threadIdx.x;
    for (int b = tid; b < NBUCKET; b += 256) lh[b] = 0;
    __syncthreads();
    int p = blockIdx.x * 256 + tid;
    const float* o = obj + (size_t)p * 18;
#pragma unroll
    for (int k = 0; k < 9; ++k) {
        float s0, s1;
        softmax2(o[2*k], o[2*k+1], s0, s1);
        if (s1 > 0.5f) {
            u32 b = (__float_as_uint(s1) - 0x3F000000u) >> 10;
            atomicAdd(&lh[b], 1u);
        }
    }
    __syncthreads();
    for (int b = tid; b < NBUCKET; b += 256) {
        u32 c = lh[b];
        if (c) atomicAdd(&hist[b], c);
    }
}

// find threshold bucket: smallest B with count(bucket >= B) >= TOPK
__global__ void k_scan(const u32* __restrict__ hist, u32* __restrict__ meta) {
    __shared__ u32 ss[1024];
    int t = threadIdx.x;
    u32 local = 0;
#pragma unroll
    for (int j = 0; j < 8; ++j) local += hist[t*8 + j];
    ss[t] = local;
    __syncthreads();
    for (int off = 1; off < 1024; off <<= 1) {
        u32 v = (t + off < 1024) ? ss[t + off] : 0;
        __syncthreads();
        ss[t] += v;
        __syncthreads();
    }
    u32 S_t = ss[t];
    u32 S_next = (t < 1023) ? ss[t+1] : 0;
    if (S_t >= TOPK && S_next < TOPK) {
        u32 cum = S_next;
        int bsel = t*8;
        for (int b = t*8 + 7; b >= t*8; --b) {
            cum += hist[b];
            if (cum >= TOPK) { bsel = b; break; }
        }
        meta[1] = (u32)bsel;
        meta[2] = cum;
    }
}

__global__ void k_compact(const float* __restrict__ obj, u32* __restrict__ meta,
                          u32* __restrict__ ckey, u32* __restrict__ cidx) {
    int p = blockIdx.x * 256 + threadIdx.x;
    u32 thr = 0x3F000000u + (meta[1] << 10);
    const float* o = obj + (size_t)p * 18;
#pragma unroll
    for (int k = 0; k < 9; ++k) {
        float s0, s1;
        softmax2(o[2*k], o[2*k+1], s0, s1);
        if (s1 > 0.5f) {
            u32 bits = __float_as_uint(s1);
            if (bits >= thr) {
                u32 pos = atomicAdd(&meta[0], 1u);
                if (pos < CAP) { ckey[pos] = bits; cidx[pos] = (u32)(p*9 + k); }
            }
        }
    }
}

#define RTILE 4096
// exact rank of each candidate: (score desc, idx asc); ranks form a permutation
__global__ void k_rank(const u32* __restrict__ meta, const u32* __restrict__ ckey,
                       const u32* __restrict__ cidx, u32* __restrict__ sel) {
    __shared__ u32 lk[RTILE];
    __shared__ u32 li[RTILE];
    int tid = threadIdx.x;
    u32 Mu = meta[0];
    int M = (int)(Mu < (u32)CAP ? Mu : (u32)CAP);
    for (int cb = blockIdx.x * 256; cb < M; cb += gridDim.x * 256) {
        int c = cb + tid;
        bool act = (c < M);
        u32 key = 0, idx = 0;
        if (act) { key = ckey[c]; idx = cidx[c]; }
        int rank = 0;
        for (int t0 = 0; t0 < M; t0 += RTILE) {
            int cnt = (M - t0 < RTILE) ? (M - t0) : RTILE;
            __syncthreads();
            for (int j = tid; j < cnt; j += 256) { lk[j] = ckey[t0+j]; li[j] = cidx[t0+j]; }
            __syncthreads();
            if (act) {
                for (int j = 0; j < cnt; ++j) {
                    u32 kj = lk[j];
                    rank += (kj > key || (kj == key && li[j] < idx)) ? 1 : 0;
                }
            }
        }
        if (act && rank < TOPK) sel[rank] = idx;
    }
}

__global__ void k_gather(const float* __restrict__ obj, const float* __restrict__ reg,
                         const float* __restrict__ anch, const u32* __restrict__ sel,
                         float* __restrict__ out,
                         float* __restrict__ nx1, float* __restrict__ ny1,
                         float* __restrict__ nx2, float* __restrict__ ny2,
                         float* __restrict__ nar, u32* __restrict__ valid) {
    int r = blockIdx.x * 256 + threadIdx.x;
    if (r >= TOPK) return;
    u32 i = sel[r];
    u32 p = i / 9u, k = i - p * 9u;
    float l0 = obj[(size_t)p*18 + 2*k];
    float l1 = obj[(size_t)p*18 + 2*k + 1];
    float s0, s1;
    softmax2(l0, l1, s0, s1);
    const float* rg = reg + (size_t)p*36 + 4*k;
    float t0 = rg[0], t1 = rg[1], t2 = rg[2], t3 = rg[3];
    const float* an = anch + (size_t)i*4;
    float a0 = an[0], a1 = an[1], a2 = an[2], a3 = an[3];
    float cx = a0 + a2/2.0f + t0*a2;
    float cy = a1 + a3/2.0f + t1*a3;
    float w = a2 * (float)::exp((double)t2);
    float h = a3 * (float)::exp((double)t3);
    float bx = cx - w/2.0f;
    float by = cy - h/2.0f;
    float x1 = fminf(fmaxf(bx, 0.0f), IMG_SZ);
    float y1 = fminf(fmaxf(by, 0.0f), IMG_SZ);
    float x2 = fminf(fmaxf(bx + w, 0.0f), IMG_SZ);
    float y2 = fminf(fmaxf(by + h, 0.0f), IMG_SZ);
    float bw = x2 - x1, bh = y2 - y1;
    out[4*r+0] = x1;
    out[4*r+1] = y1;
    out[4*r+2] = bw;
    out[4*r+3] = bh;
    out[16000 + 2*r]     = s0;
    out[16000 + 2*r + 1] = s1;
    nx1[r] = x1; ny1[r] = y1;
    nx2[r] = x1 + bw;
    ny2[r] = y1 + bh;
    nar[r] = bw * bh;
    valid[r] = (s1 > 0.5f) ? 1u : 0u;
}

__device__ __forceinline__ bool iou_gt(float x1a, float y1a, float x2a, float y2a, float aA,
                                       float x1b, float y1b, float x2b, float y2b, float aB) {
    float iw = fminf(x2a, x2b) - fmaxf(x1a, x1b);
    float ih = fminf(y2a, y2b) - fmaxf(y1a, y1b);
    iw = fmaxf(iw, 0.0f);
    ih = fmaxf(ih, 0.0f);
    float inter = iw * ih;
    float iou = inter / (aA + aB - inter + 1e-8f);
    return iou > 0.3f;
}

// ---- fast NMS path: full suppression bitmask, built grid-wide ----
// mask[i*64 + w] bit b: box i suppresses box j=w*64+b (j>i, iou>T)
// diag[i] = mask[i][i>>6]   (row i's own-group word, for the register cascade)
__global__ void k_mask(const float* __restrict__ nx1, const float* __restrict__ ny1,
                       const float* __restrict__ nx2, const float* __restrict__ ny2,
                       const float* __restrict__ nar, u64* __restrict__ mask,
                       u64* __restrict__ diag) {
    __shared__ float cx1[64], cy1[64], cx2[64], cy2[64], car[64];
    int w = blockIdx.y;
    int j0 = w * 64;
    int tid = threadIdx.x;
    if (tid < 64) {
        int j = j0 + tid;
        bool v = j < TOPK;
        cx1[tid] = v ? nx1[j] : 1e9f;
        cy1[tid] = v ? ny1[j] : 1e9f;
        cx2[tid] = v ? nx2[j] : 1e9f;
        cy2[tid] = v ? ny2[j] : 1e9f;
        car[tid] = v ? nar[j] : 0.f;
    }
    __syncthreads();
    int i = blockIdx.x * 256 + tid;
    if (i >= TOPK) return;
    float x1 = nx1[i], y1 = ny1[i], x2 = nx2[i], y2 = ny2[i], ar = nar[i];
    u64 bits = 0;
#pragma unroll
    for (int b = 0; b < 64; ++b) {
        int j = j0 + b;
        if (j < TOPK && j > i &&
            iou_gt(x1, y1, x2, y2, ar, cx1[b], cy1[b], cx2[b], cy2[b], car[b]))
            bits |= (1ull << b);
    }
    mask[(size_t)i * 64 + w] = bits;
    if (w == (i >> 6)) diag[i] = bits;
}

// single block. wave 0: register-resident greedy cascade over the bitmask;
// waves 1..15: double-buffer prefetch of the next 64-row mask block.
__global__ __launch_bounds__(1024) void k_scan_nms(const u64* __restrict__ mask,
                                                   const u64* __restrict__ diag,
                                                   const u32* __restrict__ valid,
                                                   float* __restrict__ out) {
    __shared__ u64 buf[2][64 * 64];     // 64 KB
    __shared__ u64 dlds[64 * 64];       // 32 KB (diag rows, group-major == row index)
    __shared__ u64 keep_s[64];
    int tid = threadIdx.x;
    int wave = tid >> 6, lane = tid & 63;
    const int NB = (TOPK + 63) / 64;    // 63
    // preload diag (coalesced) and batch-0 mask rows
    for (int t = tid; t < NB * 64; t += 1024)
        dlds[t] = (t < TOPK) ? diag[t] : 0ull;
    for (int q = tid; q < 64 * 64; q += 1024)
        buf[0][q] = mask[q];
    u64 kw = 0;
    if (wave == 0) {
        for (int b = 0; b < 64; ++b) {
            int t = lane * 64 + b;
            u32 v = (t < TOPK) ? valid[t] : 0u;
            kw |= ((u64)(v & 1u)) << b;
        }
    }
    __syncthreads();
    for (int g = 0; g < NB; ++g) {
        int cur = g & 1;
        if (wave != 0) {
            int gn = g + 1;
            if (gn < NB) {
                for (int q = tid - 64; q < 64 * 64; q += 960) {
                    int r = q >> 6, wd = q & 63;
                    int row = gn * 64 + r;
                    buf[gn & 1][q] = (row < TOPK) ? mask[(size_t)row * 64 + wd] : 0ull;
                }
            }
        } else {
            u64 wg = __shfl(kw, g);            // alive mask of group g (uniform)
            u64 dg = dlds[(g << 6) | lane];    // lane r: who row r suppresses in-group
            // greedy cascade: one shfl per KEPT box
            u64 am = wg, kg = 0;
            while (am) {
                int s = (int)__builtin_ctzll(am);
                kg |= (1ull << s);
                u64 sup = __shfl(dg, s);        // uniform broadcast from lane s
                am &= ~(sup | (1ull << s));
            }
            // apply group's kept rows to all words (independent LDS reads -> pipelined)
            u64 acc = 0, t = kg;
            while (t) {
                int s = (int)__builtin_ctzll(t);
                t &= t - 1;
                acc |= buf[cur][(s << 6) | lane];
            }
            kw &= ~acc;
            kw = (lane == g) ? kg : kw;        // word g is exactly the kept set
        }
        __syncthreads();
    }
    if (wave == 0) keep_s[lane] = kw;
    __syncthreads();
    for (int t = tid; t < TOPK; t += 1024)
        out[24000 + t] = ((keep_s[t >> 6] >> (t & 63)) & 1ull) ? 1.0f : 0.0f;
}

// ---- fallback single-block NMS (used if ws too small for the mask) ----
__global__ __launch_bounds__(1024) void k_nms(const float* __restrict__ gx1, const float* __restrict__ gy1,
                      const float* __restrict__ gx2, const float* __restrict__ gy2,
                      const float* __restrict__ gar, const u32* __restrict__ valid,
                      float* __restrict__ out) {
    __shared__ float lx1[TOPK], ly1[TOPK], lx2[TOPK], ly2[TOPK], lar[TOPK];
    __shared__ unsigned char lkeep[TOPK];
    __shared__ u64 supmask[64];
    __shared__ u32 klist[64];
    __shared__ int km;
    int tid = threadIdx.x;
    for (int t = tid; t < TOPK; t += 1024) {
        lx1[t] = gx1[t]; ly1[t] = gy1[t]; lx2[t] = gx2[t]; ly2[t] = gy2[t];
        lar[t] = gar[t];
        lkeep[t] = (unsigned char)valid[t];
    }
    __syncthreads();
    for (int c0 = 0; c0 < TOPK; c0 += 64) {
        int nc = (TOPK - c0 < 64) ? (TOPK - c0) : 64;
        if (tid < 64) supmask[tid] = 0ull;
        __syncthreads();
        for (int t = tid; t < 64*64; t += 1024) {
            int s = t >> 6, j = t & 63;
            if (s < j && j < nc) {
                int A = c0 + s, B = c0 + j;
                if (iou_gt(lx1[A], ly1[A], lx2[A], ly2[A], lar[A],
                           lx1[B], ly1[B], lx2[B], ly2[B], lar[B]))
                    atomicOr(&supmask[j], 1ull << s);
            }
        }
        __syncthreads();
        if (tid < 64) {
            int j = tid;
            bool alive = (j < nc) ? (lkeep[c0 + j] != 0) : false;
            u64 sm = supmask[j];
            u64 am = __ballot(alive);
            for (int s = 0; s < nc; ++s) {
                if ((am >> s) & 1ull) {
                    if ((sm >> s) & 1ull) alive = false;
                    am = __ballot(alive);
                }
            }
            if (j < nc) lkeep[c0 + j] = alive ? 1 : 0;
            u64 kmsk = __ballot(alive);
            if (alive) {
                int pos = __popcll(kmsk & ((1ull << j) - 1ull));
                klist[pos] = (u32)(c0 + j);
            }
            if (j == 0) km = __popcll(kmsk);
        }
        __syncthreads();
        int m = km;
        for (int t = c0 + 64 + tid; t < TOPK; t += 1024) {
            if (!lkeep[t]) continue;
            for (int q = 0; q < m; ++q) {
                int A = (int)klist[q];
                if (iou_gt(lx1[A], ly1[A], lx2[A], ly2[A], lar[A],
                           lx1[t], ly1[t], lx2[t], ly2[t], lar[t])) {
                    lkeep[t] = 0; break;
                }
            }
        }
        __syncthreads();
    }
    for (int t = tid; t < TOPK; t += 1024) out[24000 + t] = lkeep[t] ? 1.0f : 0.0f;
}

extern "C" void kernel_launch(void* const* d_in, const int* in_sizes, int n_in,
                              void* d_out, int out_size, void* d_ws, size_t ws_size,
                              hipStream_t stream) {
    const float* obj  = (const float*)d_in[0];
    const float* reg  = (const float*)d_in[1];
    const float* anch = (const float*)d_in[2];
    float* out = (float*)d_out;
    char* ws = (char*)d_ws;

    u32* hist = (u32*)(ws + WS_HIST);
    u32* meta = (u32*)(ws + WS_META);
    u32* ckey = (u32*)(ws + WS_CKEY);
    u32* cidx = (u32*)(ws + WS_CIDX);
    u32* sel  = (u32*)(ws + WS_SEL);
    float* nx1 = (float*)(ws + WS_NX1);
    float* ny1 = (float*)(ws + WS_NY1);
    float* nx2 = (float*)(ws + WS_NX2);
    float* ny2 = (float*)(ws + WS_NY2);
    float* nar = (float*)(ws + WS_NAR);
    u32* valid = (u32*)(ws + WS_VAL);
    u64* mask  = (u64*)(ws + WS_MASK);
    u64* diag  = (u64*)(ws + WS_DIAG);

    hipLaunchKernelGGL(k_zero, dim3((NBUCKET + 16 + 255) / 256), dim3(256), 0, stream, (u32*)ws);
    hipLaunchKernelGGL(k_hist, dim3(NPIX / 256), dim3(256), 0, stream, obj, hist);
    hipLaunchKernelGGL(k_scan, dim3(1), dim3(1024), 0, stream, hist, meta);
    hipLaunchKernelGGL(k_compact, dim3(NPIX / 256), dim3(256), 0, stream, obj, meta, ckey, cidx);
    hipLaunchKernelGGL(k_rank, dim3(64), dim3(256), 0, stream, meta, ckey, cidx, sel);
    hipLaunchKernelGGL(k_gather, dim3((TOPK + 255) / 256), dim3(256), 0, stream,
                       obj, reg, anch, sel, out, nx1, ny1, nx2, ny2, nar, valid);
    if (ws_size >= WS_END_FAST) {
        hipLaunchKernelGGL(k_mask, dim3((TOPK + 255) / 256, 64), dim3(256), 0, stream,
                           nx1, ny1, nx2, ny2, nar, mask, diag);
        hipLaunchKernelGGL(k_scan_nms, dim3(1), dim3(1024), 0, stream, mask, diag, valid, out);
    } else {
        hipLaunchKernelGGL(k_nms, dim3(1), dim3(1024), 0, stream, nx1, ny1, nx2, ny2, nar, valid, out);
    }
}

// Round 5
// 326.992 us; speedup vs baseline: 2.2613x; 2.2613x over previous
//
#include <hip/hip_runtime.h>
#include <cstdint>
#include <math.h>

#pragma clang fp contract(off)

typedef unsigned int u32;
typedef unsigned long long u64;

#define HFEAT 512
#define WFEAT 512
#define NPIX (HFEAT*WFEAT)          // 262144
#define NANCH (NPIX*9)              // 2359296
#define TOPK 4000
#define IMG_SZ 16384.0f
#define NBUCKET 8192
#define CAP 32768
#define NWORD 63                    // ceil(TOPK/64)

// ---- workspace layout (bytes) ----
#define WS_HIST 0                    // u32[8192]    32768
#define WS_META 32768                // u32[16]      64
#define WS_SUP  32832                // u64[64]      512   (supany bitmask)
#define WS_VALM 33344                // u64[64]      512   (valid bitmask)
#define WS_CKEY 33856                // u32[CAP]     131072 -> 164928
#define WS_CIDX 164928               // u32[CAP]     131072 -> 296000
#define WS_SEL  296000               // u32[TOPK]    16000  -> 312000
#define WS_NX1  312000               // f32[TOPK] each
#define WS_NY1  328000
#define WS_NX2  344000
#define WS_NY2  360000
#define WS_NAR  376000
#define WS_VAL  392000               // u32[TOPK] -> 408000
#define WS_MASK 408000               // u64[TOPK*64] = 2048000 -> 2456000
#define WS_DIAG 2456000              // u64[TOPK]    32000 -> 2488000
#define WS_END_FAST 2488000
#define ZERO_U32 ((33856)/4)         // zero hist+meta+supany+valm

// s1 = softmax(l0,l1)[1] replicating numpy f32 op-for-op, using e(max)==1.0f:
// when l1>l0: a0=l0-l1, e0=expf(a0), den=e0+1.0f, s1=1.0f/den  (bit-identical to ref)
__device__ __forceinline__ float score1(float l0, float l1) {
    float a0 = l0 - l1;
    float e0 = (float)::exp((double)a0);
    float den = e0 + 1.0f;
    return 1.0f / den;
}

// full softmax (both outputs) for the gather stage, identical op order to ref
__device__ __forceinline__ void softmax2(float l0, float l1, float& s0, float& s1) {
    float m = fmaxf(l0, l1);
    float a0 = l0 - m;
    float a1 = l1 - m;
    float e0 = (float)::exp((double)a0);
    float e1 = (float)::exp((double)a1);
    float den = e0 + e1;
    s0 = e0 / den;
    s1 = e1 / den;
}

__global__ void k_zero(u32* ws32) {
    int t = blockIdx.x * blockDim.x + threadIdx.x;
    if (t < ZERO_U32) ws32[t] = 0;
}

// histogram of f32 score bits for score > 0.5; bucket = (bits - 0x3F000000) >> 10
// coalesced: wave processes 64 consecutive anchors per iteration (float2 loads)
__global__ void k_hist(const float* __restrict__ obj, u32* __restrict__ hist) {
    __shared__ u32 lh[NBUCKET];
    int tid = threadIdx.x;
    for (int b = tid; b < NBUCKET; b += 256) lh[b] = 0;
    __syncthreads();
    const float2* o2 = (const float2*)obj;
    int base = blockIdx.x * (256 * 9);
#pragma unroll
    for (int k = 0; k < 9; ++k) {
        int a = base + k * 256 + tid;
        float2 v = o2[a];
        if (v.y > v.x) {
            float s1 = score1(v.x, v.y);
            if (s1 > 0.5f) {
                u32 b = (__float_as_uint(s1) - 0x3F000000u) >> 10;
                atomicAdd(&lh[b], 1u);
            }
        }
    }
    __syncthreads();
    for (int b = tid; b < NBUCKET; b += 256) {
        u32 c = lh[b];
        if (c) atomicAdd(&hist[b], c);
    }
}

// find threshold bucket: smallest B with count(bucket >= B) >= TOPK
__global__ void k_scan(const u32* __restrict__ hist, u32* __restrict__ meta) {
    __shared__ u32 ss[1024];
    int t = threadIdx.x;
    u32 local = 0;
#pragma unroll
    for (int j = 0; j < 8; ++j) local += hist[t*8 + j];
    ss[t] = local;
    __syncthreads();
    for (int off = 1; off < 1024; off <<= 1) {
        u32 v = (t + off < 1024) ? ss[t + off] : 0;
        __syncthreads();
        ss[t] += v;
        __syncthreads();
    }
    u32 S_t = ss[t];
    u32 S_next = (t < 1023) ? ss[t+1] : 0;
    if (S_t >= TOPK && S_next < TOPK) {
        u32 cum = S_next;
        int bsel = t*8;
        for (int b = t*8 + 7; b >= t*8; --b) {
            cum += hist[b];
            if (cum >= TOPK) { bsel = b; break; }
        }
        meta[1] = (u32)bsel;
        meta[2] = cum;
    }
}

__global__ void k_compact(const float* __restrict__ obj, u32* __restrict__ meta,
                          u32* __restrict__ ckey, u32* __restrict__ cidx) {
    int tid = threadIdx.x;
    u32 thr = 0x3F000000u + (meta[1] << 10);
    const float2* o2 = (const float2*)obj;
    int base = blockIdx.x * (256 * 9);
#pragma unroll
    for (int k = 0; k < 9; ++k) {
        int a = base + k * 256 + tid;
        float2 v = o2[a];
        if (v.y > v.x) {
            float s1 = score1(v.x, v.y);
            if (s1 > 0.5f) {
                u32 bits = __float_as_uint(s1);
                if (bits >= thr) {
                    u32 pos = atomicAdd(&meta[0], 1u);
                    if (pos < CAP) { ckey[pos] = bits; cidx[pos] = (u32)a; }
                }
            }
        }
    }
}

#define RTILE 4096
// exact rank of each candidate: (score desc, idx asc); ranks form a permutation
__global__ void k_rank(const u32* __restrict__ meta, const u32* __restrict__ ckey,
                       const u32* __restrict__ cidx, u32* __restrict__ sel) {
    __shared__ u32 lk[RTILE];
    __shared__ u32 li[RTILE];
    int tid = threadIdx.x;
    u32 Mu = meta[0];
    int M = (int)(Mu < (u32)CAP ? Mu : (u32)CAP);
    for (int cb = blockIdx.x * 256; cb < M; cb += gridDim.x * 256) {
        int c = cb + tid;
        bool act = (c < M);
        u32 key = 0, idx = 0;
        if (act) { key = ckey[c]; idx = cidx[c]; }
        int rank = 0;
        for (int t0 = 0; t0 < M; t0 += RTILE) {
            int cnt = (M - t0 < RTILE) ? (M - t0) : RTILE;
            __syncthreads();
            for (int j = tid; j < cnt; j += 256) { lk[j] = ckey[t0+j]; li[j] = cidx[t0+j]; }
            __syncthreads();
            if (act) {
                for (int j = 0; j < cnt; ++j) {
                    u32 kj = lk[j];
                    rank += (kj > key || (kj == key && li[j] < idx)) ? 1 : 0;
                }
            }
        }
        if (act && rank < TOPK) sel[rank] = idx;
    }
}

__global__ void k_gather(const float* __restrict__ obj, const float* __restrict__ reg,
                         const float* __restrict__ anch, const u32* __restrict__ sel,
                         float* __restrict__ out,
                         float* __restrict__ nx1, float* __restrict__ ny1,
                         float* __restrict__ nx2, float* __restrict__ ny2,
                         float* __restrict__ nar, u32* __restrict__ valid,
                         u64* __restrict__ valm) {
    int r = blockIdx.x * 256 + threadIdx.x;
    if (r >= TOPK) return;
    u32 i = sel[r];
    u32 p = i / 9u, k = i - p * 9u;
    float l0 = obj[(size_t)p*18 + 2*k];
    float l1 = obj[(size_t)p*18 + 2*k + 1];
    float s0, s1;
    softmax2(l0, l1, s0, s1);
    const float* rg = reg + (size_t)p*36 + 4*k;
    float t0 = rg[0], t1 = rg[1], t2 = rg[2], t3 = rg[3];
    const float* an = anch + (size_t)i*4;
    float a0 = an[0], a1 = an[1], a2 = an[2], a3 = an[3];
    float cx = a0 + a2/2.0f + t0*a2;
    float cy = a1 + a3/2.0f + t1*a3;
    float w = a2 * (float)::exp((double)t2);
    float h = a3 * (float)::exp((double)t3);
    float bx = cx - w/2.0f;
    float by = cy - h/2.0f;
    float x1 = fminf(fmaxf(bx, 0.0f), IMG_SZ);
    float y1 = fminf(fmaxf(by, 0.0f), IMG_SZ);
    float x2 = fminf(fmaxf(bx + w, 0.0f), IMG_SZ);
    float y2 = fminf(fmaxf(by + h, 0.0f), IMG_SZ);
    float bw = x2 - x1, bh = y2 - y1;
    out[4*r+0] = x1;
    out[4*r+1] = y1;
    out[4*r+2] = bw;
    out[4*r+3] = bh;
    out[16000 + 2*r]     = s0;
    out[16000 + 2*r + 1] = s1;
    nx1[r] = x1; ny1[r] = y1;
    nx2[r] = x1 + bw;
    ny2[r] = y1 + bh;
    nar[r] = bw * bh;
    u32 vld = (s1 > 0.5f) ? 1u : 0u;
    valid[r] = vld;
    u64 bm = __ballot(vld != 0u);
    if ((threadIdx.x & 63) == 0) valm[r >> 6] = bm;
}

__device__ __forceinline__ bool iou_gt(float x1a, float y1a, float x2a, float y2a, float aA,
                                       float x1b, float y1b, float x2b, float y2b, float aB) {
    float iw = fminf(x2a, x2b) - fmaxf(x1a, x1b);
    float ih = fminf(y2a, y2b) - fmaxf(y1a, y1b);
    iw = fmaxf(iw, 0.0f);
    ih = fmaxf(ih, 0.0f);
    float inter = iw * ih;
    float iou = inter / (aA + aB - inter + 1e-8f);
    return iou > 0.3f;
}

// full suppression bitmask + per-row "suppresses anyone" summary + diagonal word
__global__ void k_mask(const float* __restrict__ nx1, const float* __restrict__ ny1,
                       const float* __restrict__ nx2, const float* __restrict__ ny2,
                       const float* __restrict__ nar, u64* __restrict__ mask,
                       u64* __restrict__ diag, u64* __restrict__ supany) {
    __shared__ float cx1[64], cy1[64], cx2[64], cy2[64], car[64];
    int w = blockIdx.y;
    int j0 = w * 64;
    int tid = threadIdx.x;
    if (tid < 64) {
        int j = j0 + tid;
        bool v = j < TOPK;
        cx1[tid] = v ? nx1[j] : 1e9f;
        cy1[tid] = v ? ny1[j] : 1e9f;
        cx2[tid] = v ? nx2[j] : 1e9f;
        cy2[tid] = v ? ny2[j] : 1e9f;
        car[tid] = v ? nar[j] : 0.f;
    }
    __syncthreads();
    int i = blockIdx.x * 256 + tid;
    if (i >= TOPK) return;
    float x1 = nx1[i], y1 = ny1[i], x2 = nx2[i], y2 = ny2[i], ar = nar[i];
    u64 bits = 0;
#pragma unroll
    for (int b = 0; b < 64; ++b) {
        int j = j0 + b;
        if (j < TOPK && j > i &&
            iou_gt(x1, y1, x2, y2, ar, cx1[b], cy1[b], cx2[b], cy2[b], car[b]))
            bits |= (1ull << b);
    }
    mask[(size_t)i * 64 + w] = bits;
    if (w == (i >> 6)) diag[i] = bits;
    u64 anyb = __ballot(bits != 0ull);
    if ((tid & 63) == 0 && anyb) atomicOr(&supany[i >> 6], anyb);
}

// single wave, no barriers. Serial work scales with SUPPRESSION EVENTS, not boxes:
// groups with no alive suppressor resolve in 2 shfls; only real suppressions pay.
__global__ __launch_bounds__(64) void k_scan_nms(const u64* __restrict__ mask,
                                                 const u64* __restrict__ diag,
                                                 const u64* __restrict__ supany,
                                                 const u64* __restrict__ valm,
                                                 float* __restrict__ out) {
    __shared__ u64 dlds[NWORD * 64];   // 32KB: all diagonal words
    __shared__ u64 keep_s[64];
    int lane = threadIdx.x;            // 0..63
    // prefetch all diag (independent coalesced loads)
    for (int t = lane; t < NWORD * 64; t += 64)
        dlds[t] = (t < TOPK) ? diag[t] : 0ull;
    u64 kw = valm[lane];               // word 'lane' of keep bitmask (word 63 zeroed)
    u64 sa = supany[lane];
    __syncthreads();
    for (int g = 0; g < NWORD; ++g) {
        u64 wg  = __shfl(kw, g);       // alive in group g (uniform)
        u64 sag = __shfl(sa, g);       // rows of g with out-edges
        u64 supAlive = wg & sag;
        if (supAlive == 0ull) continue;  // every alive box kept, nothing suppressed
        u64 dg = dlds[(g << 6) | lane];  // lane r: in-group suppression word of row r
        // greedy cascade over alive suppressors only
        u64 am = wg, act = supAlive, keptSup = 0ull;
        while (act) {
            int s = (int)__builtin_ctzll(act);   // lowest alive suppressor -> kept
            u64 sup = __shfl(dg, s);
            am &= ~sup;
            keptSup |= (1ull << s);
            act &= ~(1ull << s);
            act &= am;
        }
        if (lane == g) kw = am;          // survivors of group g are kept
        // apply kept suppressors' rows to all later words (coalesced 512B reads)
        u64 t = keptSup;
        while (t) {
            int s = (int)__builtin_ctzll(t);
            t &= t - 1;
            u64 row = mask[(size_t)((g << 6) | s) * 64 + lane];
            kw &= ~row;
        }
    }
    keep_s[lane] = kw;
    __syncthreads();
    for (int t = lane; t < TOPK; t += 64)
        out[24000 + t] = ((keep_s[t >> 6] >> (t & 63)) & 1ull) ? 1.0f : 0.0f;
}

// ---- fallback single-block NMS (used if ws too small for the mask) ----
__global__ __launch_bounds__(1024) void k_nms(const float* __restrict__ gx1, const float* __restrict__ gy1,
                      const float* __restrict__ gx2, const float* __restrict__ gy2,
                      const float* __restrict__ gar, const u32* __restrict__ valid,
                      float* __restrict__ out) {
    __shared__ float lx1[TOPK], ly1[TOPK], lx2[TOPK], ly2[TOPK], lar[TOPK];
    __shared__ unsigned char lkeep[TOPK];
    __shared__ u64 supmask[64];
    __shared__ u32 klist[64];
    __shared__ int km;
    int tid = threadIdx.x;
    for (int t = tid; t < TOPK; t += 1024) {
        lx1[t] = gx1[t]; ly1[t] = gy1[t]; lx2[t] = gx2[t]; ly2[t] = gy2[t];
        lar[t] = gar[t];
        lkeep[t] = (unsigned char)valid[t];
    }
    __syncthreads();
    for (int c0 = 0; c0 < TOPK; c0 += 64) {
        int nc = (TOPK - c0 < 64) ? (TOPK - c0) : 64;
        if (tid < 64) supmask[tid] = 0ull;
        __syncthreads();
        for (int t = tid; t < 64*64; t += 1024) {
            int s = t >> 6, j = t & 63;
            if (s < j && j < nc) {
                int A = c0 + s, B = c0 + j;
                if (iou_gt(lx1[A], ly1[A], lx2[A], ly2[A], lar[A],
                           lx1[B], ly1[B], lx2[B], ly2[B], lar[B]))
                    atomicOr(&supmask[j], 1ull << s);
            }
        }
        __syncthreads();
        if (tid < 64) {
            int j = tid;
            bool alive = (j < nc) ? (lkeep[c0 + j] != 0) : false;
            u64 sm = supmask[j];
            u64 am = __ballot(alive);
            for (int s = 0; s < nc; ++s) {
                if ((am >> s) & 1ull) {
                    if ((sm >> s) & 1ull) alive = false;
                    am = __ballot(alive);
                }
            }
            if (j < nc) lkeep[c0 + j] = alive ? 1 : 0;
            u64 kmsk = __ballot(alive);
            if (alive) {
                int pos = __popcll(kmsk & ((1ull << j) - 1ull));
                klist[pos] = (u32)(c0 + j);
            }
            if (j == 0) km = __popcll(kmsk);
        }
        __syncthreads();
        int m = km;
        for (int t = c0 + 64 + tid; t < TOPK; t += 1024) {
            if (!lkeep[t]) continue;
            for (int q = 0; q < m; ++q) {
                int A = (int)klist[q];
                if (iou_gt(lx1[A], ly1[A], lx2[A], ly2[A], lar[A],
                           lx1[t], ly1[t], lx2[t], ly2[t], lar[t])) {
                    lkeep[t] = 0; break;
                }
            }
        }
        __syncthreads();
    }
    for (int t = tid; t < TOPK; t += 1024) out[24000 + t] = lkeep[t] ? 1.0f : 0.0f;
}

extern "C" void kernel_launch(void* const* d_in, const int* in_sizes, int n_in,
                              void* d_out, int out_size, void* d_ws, size_t ws_size,
                              hipStream_t stream) {
    const float* obj  = (const float*)d_in[0];
    const float* reg  = (const float*)d_in[1];
    const float* anch = (const float*)d_in[2];
    float* out = (float*)d_out;
    char* ws = (char*)d_ws;

    u32* hist = (u32*)(ws + WS_HIST);
    u32* meta = (u32*)(ws + WS_META);
    u64* supany = (u64*)(ws + WS_SUP);
    u64* valm = (u64*)(ws + WS_VALM);
    u32* ckey = (u32*)(ws + WS_CKEY);
    u32* cidx = (u32*)(ws + WS_CIDX);
    u32* sel  = (u32*)(ws + WS_SEL);
    float* nx1 = (float*)(ws + WS_NX1);
    float* ny1 = (float*)(ws + WS_NY1);
    float* nx2 = (float*)(ws + WS_NX2);
    float* ny2 = (float*)(ws + WS_NY2);
    float* nar = (float*)(ws + WS_NAR);
    u32* valid = (u32*)(ws + WS_VAL);
    u64* mask  = (u64*)(ws + WS_MASK);
    u64* diag  = (u64*)(ws + WS_DIAG);

    hipLaunchKernelGGL(k_zero, dim3((ZERO_U32 + 255) / 256), dim3(256), 0, stream, (u32*)ws);
    hipLaunchKernelGGL(k_hist, dim3(NANCH / (256*9)), dim3(256), 0, stream, obj, hist);
    hipLaunchKernelGGL(k_scan, dim3(1), dim3(1024), 0, stream, hist, meta);
    hipLaunchKernelGGL(k_compact, dim3(NANCH / (256*9)), dim3(256), 0, stream, obj, meta, ckey, cidx);
    hipLaunchKernelGGL(k_rank, dim3(64), dim3(256), 0, stream, meta, ckey, cidx, sel);
    hipLaunchKernelGGL(k_gather, dim3((TOPK + 255) / 256), dim3(256), 0, stream,
                       obj, reg, anch, sel, out, nx1, ny1, nx2, ny2, nar, valid, valm);
    if (ws_size >= WS_END_FAST) {
        hipLaunchKernelGGL(k_mask, dim3((TOPK + 255) / 256, 64), dim3(256), 0, stream,
                           nx1, ny1, nx2, ny2, nar, mask, diag, supany);
        hipLaunchKernelGGL(k_scan_nms, dim3(1), dim3(64), 0, stream, mask, diag, supany, valm, out);
    } else {
        hipLaunchKernelGGL(k_nms, dim3(1), dim3(1024), 0, stream, nx1, ny1, nx2, ny2, nar, valid, out);
    }
}

// Round 6
// 214.179 us; speedup vs baseline: 3.4524x; 1.5267x over previous
//
#include <hip/hip_runtime.h>
#include <cstdint>
#include <math.h>

#pragma clang fp contract(off)

typedef unsigned int u32;
typedef unsigned long long u64;

#define HFEAT 512
#define WFEAT 512
#define NPIX (HFEAT*WFEAT)          // 262144
#define NANCH (NPIX*9)              // 2359296
#define TOPK 4000
#define IMG_SZ 16384.0f
#define NBUCKET 8192
#define CAP 32768
#define NWORD 63                    // ceil(TOPK/64)

// ---- workspace layout (bytes) ----
#define WS_HIST 0                    // u32[8192]    32768
#define WS_META 32768                // u32[16]      64
#define WS_SUP  32832                // u64[64]      512   (supany bitmask)
#define WS_VALM 33344                // u64[64]      512   (valid bitmask)
#define WS_CKEY 33856                // u64[CAP]     262144 -> 296000  (packed key|~idx)
#define WS_SEL  296000               // u32[TOPK]    16000  -> 312000
#define WS_NX1  312000               // f32[TOPK] each
#define WS_NY1  328000
#define WS_NX2  344000
#define WS_NY2  360000
#define WS_NAR  376000
#define WS_VAL  392000               // u32[TOPK] -> 408000
#define WS_MASK 408000               // u64[TOPK*64] = 2048000 -> 2456000
#define WS_DIAG 2456000              // u64[TOPK]    32000 -> 2488000
#define WS_END_FAST 2488000
#define ZERO_U32 ((33856)/4)         // zero hist+meta+supany+valm

// s1 = softmax(l0,l1)[1] replicating numpy f32 op-for-op, using e(max)==1.0f:
// when l1>l0: a0=l0-l1, e0=expf(a0), den=e0+1.0f, s1=1.0f/den  (bit-identical to ref)
__device__ __forceinline__ float score1(float l0, float l1) {
    float a0 = l0 - l1;
    float e0 = (float)::exp((double)a0);
    float den = e0 + 1.0f;
    return 1.0f / den;
}

// full softmax (both outputs) for the gather stage, identical op order to ref
__device__ __forceinline__ void softmax2(float l0, float l1, float& s0, float& s1) {
    float m = fmaxf(l0, l1);
    float a0 = l0 - m;
    float a1 = l1 - m;
    float e0 = (float)::exp((double)a0);
    float e1 = (float)::exp((double)a1);
    float den = e0 + e1;
    s0 = e0 / den;
    s1 = e1 / den;
}

__global__ void k_zero(u32* ws32) {
    int t = blockIdx.x * blockDim.x + threadIdx.x;
    if (t < ZERO_U32) ws32[t] = 0;
}

// histogram of f32 score bits for score > 0.5; bucket = (bits - 0x3F000000) >> 10
// coalesced: wave processes 64 consecutive anchors per iteration (float2 loads)
__global__ void k_hist(const float* __restrict__ obj, u32* __restrict__ hist) {
    __shared__ u32 lh[NBUCKET];
    int tid = threadIdx.x;
    for (int b = tid; b < NBUCKET; b += 256) lh[b] = 0;
    __syncthreads();
    const float2* o2 = (const float2*)obj;
    int base = blockIdx.x * (256 * 9);
#pragma unroll
    for (int k = 0; k < 9; ++k) {
        int a = base + k * 256 + tid;
        float2 v = o2[a];
        if (v.y > v.x) {
            float s1 = score1(v.x, v.y);
            if (s1 > 0.5f) {
                u32 b = (__float_as_uint(s1) - 0x3F000000u) >> 10;
                atomicAdd(&lh[b], 1u);
            }
        }
    }
    __syncthreads();
    for (int b = tid; b < NBUCKET; b += 256) {
        u32 c = lh[b];
        if (c) atomicAdd(&hist[b], c);
    }
}

// find threshold bucket: smallest B with count(bucket >= B) >= TOPK
__global__ void k_scan(const u32* __restrict__ hist, u32* __restrict__ meta) {
    __shared__ u32 ss[1024];
    int t = threadIdx.x;
    u32 local = 0;
#pragma unroll
    for (int j = 0; j < 8; ++j) local += hist[t*8 + j];
    ss[t] = local;
    __syncthreads();
    for (int off = 1; off < 1024; off <<= 1) {
        u32 v = (t + off < 1024) ? ss[t + off] : 0;
        __syncthreads();
        ss[t] += v;
        __syncthreads();
    }
    u32 S_t = ss[t];
    u32 S_next = (t < 1023) ? ss[t+1] : 0;
    if (S_t >= TOPK && S_next < TOPK) {
        u32 cum = S_next;
        int bsel = t*8;
        for (int b = t*8 + 7; b >= t*8; --b) {
            cum += hist[b];
            if (cum >= TOPK) { bsel = b; break; }
        }
        meta[1] = (u32)bsel;
        meta[2] = cum;
    }
}

// packed candidate: (score_bits << 32) | ~idx  -> single u64 compare gives
// (score desc, idx asc) ordering
__global__ void k_compact(const float* __restrict__ obj, u32* __restrict__ meta,
                          u64* __restrict__ ckeyp) {
    int tid = threadIdx.x;
    u32 thr = 0x3F000000u + (meta[1] << 10);
    const float2* o2 = (const float2*)obj;
    int base = blockIdx.x * (256 * 9);
#pragma unroll
    for (int k = 0; k < 9; ++k) {
        int a = base + k * 256 + tid;
        float2 v = o2[a];
        if (v.y > v.x) {
            float s1 = score1(v.x, v.y);
            if (s1 > 0.5f) {
                u32 bits = __float_as_uint(s1);
                if (bits >= thr) {
                    u32 pos = atomicAdd(&meta[0], 1u);
                    if (pos < CAP) ckeyp[pos] = ((u64)bits << 32) | (u32)(~(u32)a);
                }
            }
        }
    }
}

#define RTILE 4096
// exact rank via packed u64 compare; fixed-trip unrolled inner loop (zeros pad)
__global__ void k_rank(const u32* __restrict__ meta, const u64* __restrict__ ckeyp,
                       u32* __restrict__ sel) {
    __shared__ u64 lk[RTILE];
    int tid = threadIdx.x;
    u32 Mu = meta[0];
    int M = (int)(Mu < (u32)CAP ? Mu : (u32)CAP);
    for (int cb = blockIdx.x * 256; cb < M; cb += gridDim.x * 256) {
        int c = cb + tid;
        bool act = (c < M);
        u64 mypk = act ? ckeyp[c] : 0ull;
        int rank = 0;
        for (int t0 = 0; t0 < M; t0 += RTILE) {
            __syncthreads();
            for (int j = tid; j < RTILE; j += 256)
                lk[j] = (t0 + j < M) ? ckeyp[t0 + j] : 0ull;
            __syncthreads();
#pragma unroll 16
            for (int j = 0; j < RTILE; ++j)
                rank += (lk[j] > mypk) ? 1 : 0;
        }
        if (act && rank < TOPK) sel[rank] = ~(u32)(mypk & 0xFFFFFFFFull);
    }
}

__global__ void k_gather(const float* __restrict__ obj, const float* __restrict__ reg,
                         const float* __restrict__ anch, const u32* __restrict__ sel,
                         float* __restrict__ out,
                         float* __restrict__ nx1, float* __restrict__ ny1,
                         float* __restrict__ nx2, float* __restrict__ ny2,
                         float* __restrict__ nar, u32* __restrict__ valid,
                         u64* __restrict__ valm) {
    int r = blockIdx.x * 256 + threadIdx.x;
    if (r >= TOPK) return;
    u32 i = sel[r];
    u32 p = i / 9u, k = i - p * 9u;
    float l0 = obj[(size_t)p*18 + 2*k];
    float l1 = obj[(size_t)p*18 + 2*k + 1];
    float s0, s1;
    softmax2(l0, l1, s0, s1);
    const float* rg = reg + (size_t)p*36 + 4*k;
    float t0 = rg[0], t1 = rg[1], t2 = rg[2], t3 = rg[3];
    const float* an = anch + (size_t)i*4;
    float a0 = an[0], a1 = an[1], a2 = an[2], a3 = an[3];
    float cx = a0 + a2/2.0f + t0*a2;
    float cy = a1 + a3/2.0f + t1*a3;
    float w = a2 * (float)::exp((double)t2);
    float h = a3 * (float)::exp((double)t3);
    float bx = cx - w/2.0f;
    float by = cy - h/2.0f;
    float x1 = fminf(fmaxf(bx, 0.0f), IMG_SZ);
    float y1 = fminf(fmaxf(by, 0.0f), IMG_SZ);
    float x2 = fminf(fmaxf(bx + w, 0.0f), IMG_SZ);
    float y2 = fminf(fmaxf(by + h, 0.0f), IMG_SZ);
    float bw = x2 - x1, bh = y2 - y1;
    out[4*r+0] = x1;
    out[4*r+1] = y1;
    out[4*r+2] = bw;
    out[4*r+3] = bh;
    out[16000 + 2*r]     = s0;
    out[16000 + 2*r + 1] = s1;
    nx1[r] = x1; ny1[r] = y1;
    nx2[r] = x1 + bw;
    ny2[r] = y1 + bh;
    nar[r] = bw * bh;
    u32 vld = (s1 > 0.5f) ? 1u : 0u;
    valid[r] = vld;
    u64 bm = __ballot(vld != 0u);
    if ((threadIdx.x & 63) == 0) valm[r >> 6] = bm;
}

__device__ __forceinline__ bool iou_gt(float x1a, float y1a, float x2a, float y2a, float aA,
                                       float x1b, float y1b, float x2b, float y2b, float aB) {
    float iw = fminf(x2a, x2b) - fmaxf(x1a, x1b);
    float ih = fminf(y2a, y2b) - fmaxf(y1a, y1b);
    iw = fmaxf(iw, 0.0f);
    ih = fmaxf(ih, 0.0f);
    float inter = iw * ih;
    float iou = inter / (aA + aB - inter + 1e-8f);
    return iou > 0.3f;
}

// full suppression bitmask + per-row "suppresses anyone" summary + diagonal word
__global__ void k_mask(const float* __restrict__ nx1, const float* __restrict__ ny1,
                       const float* __restrict__ nx2, const float* __restrict__ ny2,
                       const float* __restrict__ nar, u64* __restrict__ mask,
                       u64* __restrict__ diag, u64* __restrict__ supany) {
    __shared__ float cx1[64], cy1[64], cx2[64], cy2[64], car[64];
    int w = blockIdx.y;
    int j0 = w * 64;
    int tid = threadIdx.x;
    if (tid < 64) {
        int j = j0 + tid;
        bool v = j < TOPK;
        cx1[tid] = v ? nx1[j] : 1e9f;
        cy1[tid] = v ? ny1[j] : 1e9f;
        cx2[tid] = v ? nx2[j] : 1e9f;
        cy2[tid] = v ? ny2[j] : 1e9f;
        car[tid] = v ? nar[j] : 0.f;
    }
    __syncthreads();
    int i = blockIdx.x * 256 + tid;
    if (i >= TOPK) return;
    float x1 = nx1[i], y1 = ny1[i], x2 = nx2[i], y2 = ny2[i], ar = nar[i];
    u64 bits = 0;
#pragma unroll
    for (int b = 0; b < 64; ++b) {
        int j = j0 + b;
        if (j < TOPK && j > i &&
            iou_gt(x1, y1, x2, y2, ar, cx1[b], cy1[b], cx2[b], cy2[b], car[b]))
            bits |= (1ull << b);
    }
    mask[(size_t)i * 64 + w] = bits;
    if (w == (i >> 6)) diag[i] = bits;
    u64 anyb = __ballot(bits != 0ull);
    if ((tid & 63) == 0 && anyb) atomicOr(&supany[i >> 6], anyb);
}

// single wave, no barriers. Serial work scales with SUPPRESSION EVENTS, not boxes.
__global__ __launch_bounds__(64) void k_scan_nms(const u64* __restrict__ mask,
                                                 const u64* __restrict__ diag,
                                                 const u64* __restrict__ supany,
                                                 const u64* __restrict__ valm,
                                                 float* __restrict__ out) {
    __shared__ u64 dlds[NWORD * 64];   // 32KB: all diagonal words
    __shared__ u64 keep_s[64];
    int lane = threadIdx.x;            // 0..63
    for (int t = lane; t < NWORD * 64; t += 64)
        dlds[t] = (t < TOPK) ? diag[t] : 0ull;
    u64 kw = valm[lane];
    u64 sa = supany[lane];
    __syncthreads();
    for (int g = 0; g < NWORD; ++g) {
        u64 wg  = __shfl(kw, g);
        u64 sag = __shfl(sa, g);
        u64 supAlive = wg & sag;
        if (supAlive == 0ull) continue;
        u64 dg = dlds[(g << 6) | lane];
        u64 am = wg, act = supAlive, keptSup = 0ull;
        while (act) {
            int s = (int)__builtin_ctzll(act);
            u64 sup = __shfl(dg, s);
            am &= ~sup;
            keptSup |= (1ull << s);
            act &= ~(1ull << s);
            act &= am;
        }
        if (lane == g) kw = am;
        u64 t = keptSup;
        while (t) {
            int s = (int)__builtin_ctzll(t);
            t &= t - 1;
            u64 row = mask[(size_t)((g << 6) | s) * 64 + lane];
            kw &= ~row;
        }
    }
    keep_s[lane] = kw;
    __syncthreads();
    for (int t = lane; t < TOPK; t += 64)
        out[24000 + t] = ((keep_s[t >> 6] >> (t & 63)) & 1ull) ? 1.0f : 0.0f;
}

extern "C" void kernel_launch(void* const* d_in, const int* in_sizes, int n_in,
                              void* d_out, int out_size, void* d_ws, size_t ws_size,
                              hipStream_t stream) {
    const float* obj  = (const float*)d_in[0];
    const float* reg  = (const float*)d_in[1];
    const float* anch = (const float*)d_in[2];
    float* out = (float*)d_out;
    char* ws = (char*)d_ws;

    u32* hist = (u32*)(ws + WS_HIST);
    u32* meta = (u32*)(ws + WS_META);
    u64* supany = (u64*)(ws + WS_SUP);
    u64* valm = (u64*)(ws + WS_VALM);
    u64* ckeyp = (u64*)(ws + WS_CKEY);
    u32* sel  = (u32*)(ws + WS_SEL);
    float* nx1 = (float*)(ws + WS_NX1);
    float* ny1 = (float*)(ws + WS_NY1);
    float* nx2 = (float*)(ws + WS_NX2);
    float* ny2 = (float*)(ws + WS_NY2);
    float* nar = (float*)(ws + WS_NAR);
    u32* valid = (u32*)(ws + WS_VAL);
    u64* mask  = (u64*)(ws + WS_MASK);
    u64* diag  = (u64*)(ws + WS_DIAG);

    hipLaunchKernelGGL(k_zero, dim3((ZERO_U32 + 255) / 256), dim3(256), 0, stream, (u32*)ws);
    hipLaunchKernelGGL(k_hist, dim3(NANCH / (256*9)), dim3(256), 0, stream, obj, hist);
    hipLaunchKernelGGL(k_scan, dim3(1), dim3(1024), 0, stream, hist, meta);
    hipLaunchKernelGGL(k_compact, dim3(NANCH / (256*9)), dim3(256), 0, stream, obj, meta, ckeyp);
    hipLaunchKernelGGL(k_rank, dim3(64), dim3(256), 0, stream, meta, ckeyp, sel);
    hipLaunchKernelGGL(k_gather, dim3((TOPK + 255) / 256), dim3(256), 0, stream,
                       obj, reg, anch, sel, out, nx1, ny1, nx2, ny2, nar, valid, valm);
    hipLaunchKernelGGL(k_mask, dim3((TOPK + 255) / 256, 64), dim3(256), 0, stream,
                       nx1, ny1, nx2, ny2, nar, mask, diag, supany);
    hipLaunchKernelGGL(k_scan_nms, dim3(1), dim3(64), 0, stream, mask, diag, supany, valm, out);
}

// Round 7
// 181.009 us; speedup vs baseline: 4.0851x; 1.1833x over previous
//
#include <hip/hip_runtime.h>
#include <cstdint>
#include <math.h>

#pragma clang fp contract(off)

typedef unsigned int u32;
typedef unsigned long long u64;

#define HFEAT 512
#define WFEAT 512
#define NPIX (HFEAT*WFEAT)          // 262144
#define NANCH (NPIX*9)              // 2359296
#define TOPK 4000
#define IMG_SZ 16384.0f
#define NBUCKET 8192
#define CAP 32768
#define NWORD 63                    // ceil(TOPK/64)
#define RCACHE 224                  // suppressor-row LDS cache slots

// ---- workspace layout (bytes) ----
#define WS_HIST 0                    // u32[8192]    32768
#define WS_META 32768                // u32[16]      64
#define WS_SUP  32832                // u64[64]      512   (supany bitmask)
#define WS_VALM 33344                // u64[64]      512   (valid bitmask)
#define WS_CKEY 33856                // u64[CAP]     262144 -> 296000  (packed s1|~idx)
#define WS_SEL  296000               // u32[TOPK]    16000  -> 312000
#define WS_NX1  312000               // f32[TOPK] each
#define WS_NY1  328000
#define WS_NX2  344000
#define WS_NY2  360000
#define WS_NAR  376000
#define WS_VAL  392000               // u32[TOPK] -> 408000
#define WS_MASK 408000               // u64[TOPK*64] = 2048000 -> 2456000
#define WS_DIAG 2456000              // u64[TOPK]    32000 -> 2488000
#define ZERO_U32 ((33856)/4)         // zero hist+meta+supany+valm

// d-bits bucket: d < -2 only; larger bucket == more negative d == higher score.
// bucket width = 4096 f32-ulps of d  (~2e-3 at d~-4): an s1-ulp tie spans ~3.8e-6
// in d, so equal-s1 candidates are always within +-1 bucket.
__device__ __forceinline__ int dbucket(float d) {
    u32 bits = __float_as_uint(d);
    int sb = (int)(bits - 0xC0000000u);   // >=0 iff d <= -2
    int b = sb >> 12;
    return (b > (NBUCKET - 1)) ? (NBUCKET - 1) : b;
}

// exact f32 s1 for l1>l0, bit-identical to numpy softmax chain:
// m=l1, a0=l0-l1, e1=exp(0)=1.0f, den=e0+1.0f, s1=1.0f/den
__device__ __forceinline__ float score1(float d) {
    float e0 = (float)::exp((double)d);
    float den = e0 + 1.0f;
    return 1.0f / den;
}

// full softmax (both outputs) for the gather stage, identical op order to ref
__device__ __forceinline__ void softmax2(float l0, float l1, float& s0, float& s1) {
    float m = fmaxf(l0, l1);
    float a0 = l0 - m;
    float a1 = l1 - m;
    float e0 = (float)::exp((double)a0);
    float e1 = (float)::exp((double)a1);
    float den = e0 + e1;
    s0 = e0 / den;
    s1 = e1 / den;
}

__global__ void k_zero(u32* ws32) {
    int t = blockIdx.x * blockDim.x + threadIdx.x;
    if (t < ZERO_U32) ws32[t] = 0;
}

// histogram of d-buckets (exp-free streaming pass)
__global__ void k_hist(const float* __restrict__ obj, u32* __restrict__ hist) {
    __shared__ u32 lh[NBUCKET];
    int tid = threadIdx.x;
    for (int b = tid; b < NBUCKET; b += 256) lh[b] = 0;
    __syncthreads();
    const float2* o2 = (const float2*)obj;
    int base = blockIdx.x * (256 * 9);
#pragma unroll
    for (int k = 0; k < 9; ++k) {
        int a = base + k * 256 + tid;
        float2 v = o2[a];
        float d = v.x - v.y;
        if (d < -2.0f) atomicAdd(&lh[dbucket(d)], 1u);
    }
    __syncthreads();
    for (int b = tid; b < NBUCKET; b += 256) {
        u32 c = lh[b];
        if (c) atomicAdd(&hist[b], c);
    }
}

// threshold bucket: smallest B with count(bucket >= B) >= TOPK; -1 margin for s1 ties
__global__ void k_scan(const u32* __restrict__ hist, u32* __restrict__ meta) {
    __shared__ u32 ss[1024];
    int t = threadIdx.x;
    u32 local = 0;
#pragma unroll
    for (int j = 0; j < 8; ++j) local += hist[t*8 + j];
    ss[t] = local;
    __syncthreads();
    for (int off = 1; off < 1024; off <<= 1) {
        u32 v = (t + off < 1024) ? ss[t + off] : 0;
        __syncthreads();
        ss[t] += v;
        __syncthreads();
    }
    u32 S_t = ss[t];
    u32 S_next = (t < 1023) ? ss[t+1] : 0;
    if (S_t >= TOPK && S_next < TOPK) {
        u32 cum = S_next;
        int bsel = t*8;
        for (int b = t*8 + 7; b >= t*8; --b) {
            cum += hist[b];
            if (cum >= TOPK) { bsel = b; break; }
        }
        meta[1] = (u32)((bsel > 0) ? bsel - 1 : 0);   // include one-bucket tie margin
        meta[2] = cum;
    }
}

// compact passers; exact s1 (fp64 exp) only for the ~4k passers
__global__ void k_compact(const float* __restrict__ obj, u32* __restrict__ meta,
                          u64* __restrict__ ckeyp) {
    int tid = threadIdx.x;
    int thr = (int)meta[1];
    const float2* o2 = (const float2*)obj;
    int base = blockIdx.x * (256 * 9);
#pragma unroll
    for (int k = 0; k < 9; ++k) {
        int a = base + k * 256 + tid;
        float2 v = o2[a];
        float d = v.x - v.y;
        if (d < -2.0f && dbucket(d) >= thr) {
            float s1 = score1(d);
            if (s1 > 0.5f) {
                u32 bits = __float_as_uint(s1);
                u32 pos = atomicAdd(&meta[0], 1u);
                if (pos < CAP) ckeyp[pos] = ((u64)bits << 32) | (u32)(~(u32)a);
            }
        }
    }
}

#define RTILE 4096
// exact rank via packed u64 compare; fixed-trip unrolled inner loop (zeros pad)
__global__ void k_rank(const u32* __restrict__ meta, const u64* __restrict__ ckeyp,
                       u32* __restrict__ sel) {
    __shared__ u64 lk[RTILE];
    int tid = threadIdx.x;
    u32 Mu = meta[0];
    int M = (int)(Mu < (u32)CAP ? Mu : (u32)CAP);
    for (int cb = blockIdx.x * 256; cb < M; cb += gridDim.x * 256) {
        int c = cb + tid;
        bool act = (c < M);
        u64 mypk = act ? ckeyp[c] : 0ull;
        int rank = 0;
        for (int t0 = 0; t0 < M; t0 += RTILE) {
            __syncthreads();
            for (int j = tid; j < RTILE; j += 256)
                lk[j] = (t0 + j < M) ? ckeyp[t0 + j] : 0ull;
            __syncthreads();
#pragma unroll 16
            for (int j = 0; j < RTILE; ++j)
                rank += (lk[j] > mypk) ? 1 : 0;
        }
        if (act && rank < TOPK) sel[rank] = ~(u32)(mypk & 0xFFFFFFFFull);
    }
}

__global__ void k_gather(const float* __restrict__ obj, const float* __restrict__ reg,
                         const float* __restrict__ anch, const u32* __restrict__ sel,
                         float* __restrict__ out,
                         float* __restrict__ nx1, float* __restrict__ ny1,
                         float* __restrict__ nx2, float* __restrict__ ny2,
                         float* __restrict__ nar, u32* __restrict__ valid,
                         u64* __restrict__ valm) {
    int r = blockIdx.x * 256 + threadIdx.x;
    if (r >= TOPK) return;
    u32 i = sel[r];
    u32 p = i / 9u, k = i - p * 9u;
    float l0 = obj[(size_t)p*18 + 2*k];
    float l1 = obj[(size_t)p*18 + 2*k + 1];
    float s0, s1;
    softmax2(l0, l1, s0, s1);
    const float* rg = reg + (size_t)p*36 + 4*k;
    float t0 = rg[0], t1 = rg[1], t2 = rg[2], t3 = rg[3];
    const float* an = anch + (size_t)i*4;
    float a0 = an[0], a1 = an[1], a2 = an[2], a3 = an[3];
    float cx = a0 + a2/2.0f + t0*a2;
    float cy = a1 + a3/2.0f + t1*a3;
    float w = a2 * (float)::exp((double)t2);
    float h = a3 * (float)::exp((double)t3);
    float bx = cx - w/2.0f;
    float by = cy - h/2.0f;
    float x1 = fminf(fmaxf(bx, 0.0f), IMG_SZ);
    float y1 = fminf(fmaxf(by, 0.0f), IMG_SZ);
    float x2 = fminf(fmaxf(bx + w, 0.0f), IMG_SZ);
    float y2 = fminf(fmaxf(by + h, 0.0f), IMG_SZ);
    float bw = x2 - x1, bh = y2 - y1;
    out[4*r+0] = x1;
    out[4*r+1] = y1;
    out[4*r+2] = bw;
    out[4*r+3] = bh;
    out[16000 + 2*r]     = s0;
    out[16000 + 2*r + 1] = s1;
    nx1[r] = x1; ny1[r] = y1;
    nx2[r] = x1 + bw;
    ny2[r] = y1 + bh;
    nar[r] = bw * bh;
    u32 vld = (s1 > 0.5f) ? 1u : 0u;
    valid[r] = vld;
    u64 bm = __ballot(vld != 0u);
    if ((threadIdx.x & 63) == 0) valm[r >> 6] = bm;
}

__device__ __forceinline__ bool iou_gt(float x1a, float y1a, float x2a, float y2a, float aA,
                                       float x1b, float y1b, float x2b, float y2b, float aB) {
    float iw = fminf(x2a, x2b) - fmaxf(x1a, x1b);
    float ih = fminf(y2a, y2b) - fmaxf(y1a, y1b);
    iw = fmaxf(iw, 0.0f);
    ih = fmaxf(ih, 0.0f);
    float inter = iw * ih;
    float iou = inter / (aA + aB - inter + 1e-8f);
    return iou > 0.3f;
}

// full suppression bitmask + per-row "suppresses anyone" summary + diagonal word
__global__ void k_mask(const float* __restrict__ nx1, const float* __restrict__ ny1,
                       const float* __restrict__ nx2, const float* __restrict__ ny2,
                       const float* __restrict__ nar, u64* __restrict__ mask,
                       u64* __restrict__ diag, u64* __restrict__ supany) {
    __shared__ float cx1[64], cy1[64], cx2[64], cy2[64], car[64];
    int w = blockIdx.y;
    int j0 = w * 64;
    int tid = threadIdx.x;
    if (tid < 64) {
        int j = j0 + tid;
        bool v = j < TOPK;
        cx1[tid] = v ? nx1[j] : 1e9f;
        cy1[tid] = v ? ny1[j] : 1e9f;
        cx2[tid] = v ? nx2[j] : 1e9f;
        cy2[tid] = v ? ny2[j] : 1e9f;
        car[tid] = v ? nar[j] : 0.f;
    }
    __syncthreads();
    int i = blockIdx.x * 256 + tid;
    if (i >= TOPK) return;
    float x1 = nx1[i], y1 = ny1[i], x2 = nx2[i], y2 = ny2[i], ar = nar[i];
    u64 bits = 0;
#pragma unroll
    for (int b = 0; b < 64; ++b) {
        int j = j0 + b;
        if (j < TOPK && j > i &&
            iou_gt(x1, y1, x2, y2, ar, cx1[b], cy1[b], cx2[b], cy2[b], car[b]))
            bits |= (1ull << b);
    }
    mask[(size_t)i * 64 + w] = bits;
    if (w == (i >> 6)) diag[i] = bits;
    u64 anyb = __ballot(bits != 0ull);
    if ((tid & 63) == 0 && anyb) atomicOr(&supany[i >> 6], anyb);
}

// 512 threads: all waves preload suppressor rows + diag into LDS; wave 0 scans.
// Serial chain per suppression event is now LDS-latency, not HBM-latency.
__global__ __launch_bounds__(512) void k_scan_nms(const u64* __restrict__ mask,
                                                  const u64* __restrict__ diag,
                                                  const u64* __restrict__ supany,
                                                  const u64* __restrict__ valm,
                                                  float* __restrict__ out) {
    __shared__ u64 dlds[NWORD * 64];     // 32256 B: diagonal words
    __shared__ u64 cache[RCACHE * 64];   // 114688 B: suppressor rows
    __shared__ u32 rowlist[RCACHE];
    __shared__ u32 nrows_s;
    __shared__ u64 keep_s[64];
    int tid = threadIdx.x;
    int wave = tid >> 6, lane = tid & 63;

    // diag preload (all waves, independent coalesced loads)
    for (int t = tid; t < NWORD * 64; t += 512)
        dlds[t] = (t < TOPK) ? diag[t] : 0ull;

    int excl = 0;      // exclusive prefix of suppressor counts per word (wave0 regs)
    u64 sa = 0;
    if (wave == 0) {
        sa = supany[lane];
        int c = (int)__popcll(sa);
        int pfx = c;
        for (int off = 1; off < 64; off <<= 1) {
            int n = __shfl_up(pfx, off);
            if (lane >= off) pfx += n;
        }
        excl = pfx - c;
        int total = __shfl(pfx, 63);
        if (lane == 0) nrows_s = (u32)((total < RCACHE) ? total : RCACHE);
        // emit row list + slots (slot == global enumeration order of supany bits)
        int s = excl; u64 t = sa;
        while (t) {
            int b = (int)__builtin_ctzll(t); t &= t - 1;
            if (s < RCACHE) rowlist[s] = (u32)((lane << 6) | b);
            s++;
        }
    }
    __syncthreads();
    int R = (int)nrows_s;
    // fill cache: 8-deep batched independent loads across 8 waves
    {
        const int TW = RCACHE * 64;
        for (int t0 = tid; t0 < TW; t0 += 512 * 8) {
            u64 v[8];
#pragma unroll
            for (int u = 0; u < 8; ++u) {
                int t = t0 + u * 512;
                int sl = t >> 6;
                int row = (t < TW && sl < R) ? (int)rowlist[sl] : 0;
                v[u] = (t < TW) ? mask[(size_t)row * 64 + (t & 63)] : 0ull;
            }
#pragma unroll
            for (int u = 0; u < 8; ++u) {
                int t = t0 + u * 512;
                if (t < TW) cache[t] = v[u];
            }
        }
    }
    __syncthreads();
    if (wave == 0) {
        u64 kw = valm[lane];
        u64 gm = __ballot((sa & kw) != 0ull);   // event-group superset
        while (gm) {
            int g = (int)__builtin_ctzll(gm); gm &= gm - 1;
            u64 wg  = __shfl(kw, g);
            u64 sag = __shfl(sa, g);
            u64 supAlive = wg & sag;
            if (supAlive == 0ull) continue;
            int sbase = __shfl(excl, g);
            u64 dg = dlds[(g << 6) | lane];
            // greedy cascade within group (one shfl per kept suppressor)
            u64 am = wg, act = supAlive, keptSup = 0ull;
            while (act) {
                int s = (int)__builtin_ctzll(act);
                u64 sup = __shfl(dg, s);
                am &= ~sup;
                keptSup |= (1ull << s);
                act &= ~(1ull << s);
                act &= am;
            }
            // apply kept suppressors' rows from LDS cache (2-deep batch)
            u64 acc = 0, t = keptSup;
            while (t) {
                int s1b = (int)__builtin_ctzll(t); t &= t - 1;
                int sl1 = sbase + (int)__popcll(sag & ((1ull << s1b) - 1ull));
                if (t) {
                    int s2b = (int)__builtin_ctzll(t); t &= t - 1;
                    int sl2 = sbase + (int)__popcll(sag & ((1ull << s2b) - 1ull));
                    u64 ra = (sl1 < RCACHE) ? cache[(sl1 << 6) | lane]
                                            : mask[(size_t)((g << 6) | s1b) * 64 + lane];
                    u64 rb = (sl2 < RCACHE) ? cache[(sl2 << 6) | lane]
                                            : mask[(size_t)((g << 6) | s2b) * 64 + lane];
                    acc |= ra | rb;
                } else {
                    acc |= (sl1 < RCACHE) ? cache[(sl1 << 6) | lane]
                                          : mask[(size_t)((g << 6) | s1b) * 64 + lane];
                }
            }
            kw &= ~acc;   // rows carry only j>i bits; word g result == cascade's am
        }
        keep_s[lane] = kw;
    }
    __syncthreads();
    for (int t = tid; t < TOPK; t += 512)
        out[24000 + t] = ((keep_s[t >> 6] >> (t & 63)) & 1ull) ? 1.0f : 0.0f;
}

extern "C" void kernel_launch(void* const* d_in, const int* in_sizes, int n_in,
                              void* d_out, int out_size, void* d_ws, size_t ws_size,
                              hipStream_t stream) {
    const float* obj  = (const float*)d_in[0];
    const float* reg  = (const float*)d_in[1];
    const float* anch = (const float*)d_in[2];
    float* out = (float*)d_out;
    char* ws = (char*)d_ws;

    u32* hist = (u32*)(ws + WS_HIST);
    u32* meta = (u32*)(ws + WS_META);
    u64* supany = (u64*)(ws + WS_SUP);
    u64* valm = (u64*)(ws + WS_VALM);
    u64* ckeyp = (u64*)(ws + WS_CKEY);
    u32* sel  = (u32*)(ws + WS_SEL);
    float* nx1 = (float*)(ws + WS_NX1);
    float* ny1 = (float*)(ws + WS_NY1);
    float* nx2 = (float*)(ws + WS_NX2);
    float* ny2 = (float*)(ws + WS_NY2);
    float* nar = (float*)(ws + WS_NAR);
    u32* valid = (u32*)(ws + WS_VAL);
    u64* mask  = (u64*)(ws + WS_MASK);
    u64* diag  = (u64*)(ws + WS_DIAG);

    hipLaunchKernelGGL(k_zero, dim3((ZERO_U32 + 255) / 256), dim3(256), 0, stream, (u32*)ws);
    hipLaunchKernelGGL(k_hist, dim3(NANCH / (256*9)), dim3(256), 0, stream, obj, hist);
    hipLaunchKernelGGL(k_scan, dim3(1), dim3(1024), 0, stream, hist, meta);
    hipLaunchKernelGGL(k_compact, dim3(NANCH / (256*9)), dim3(256), 0, stream, obj, meta, ckeyp);
    hipLaunchKernelGGL(k_rank, dim3(64), dim3(256), 0, stream, meta, ckeyp, sel);
    hipLaunchKernelGGL(k_gather, dim3((TOPK + 255) / 256), dim3(256), 0, stream,
                       obj, reg, anch, sel, out, nx1, ny1, nx2, ny2, nar, valid, valm);
    hipLaunchKernelGGL(k_mask, dim3((TOPK + 255) / 256, 64), dim3(256), 0, stream,
                       nx1, ny1, nx2, ny2, nar, mask, diag, supany);
    hipLaunchKernelGGL(k_scan_nms, dim3(1), dim3(512), 0, stream, mask, diag, supany, valm, out);
}

// Round 8
// 111.947 us; speedup vs baseline: 6.6052x; 1.6169x over previous
//
#include <hip/hip_runtime.h>
#include <cstdint>
#include <math.h>

#pragma clang fp contract(off)

typedef unsigned int u32;
typedef unsigned long long u64;

#define HFEAT 512
#define WFEAT 512
#define NPIX (HFEAT*WFEAT)          // 262144
#define NANCH (NPIX*9)              // 2359296
#define TOPK 4000
#define IMG_SZ 16384.0f
#define NBUCKET 8192
#define CAP 32768
#define NWORD 63                    // ceil(TOPK/64)
#define RCACHE 224                  // suppressor-row LDS cache slots
#define COARSE_CUT (-3.5f)
#define COARSE_BUK 1537             // fast path iff thr bucket >= this (strictly past -3.5 bucket)

// ---- workspace layout (bytes) ----
#define WS_HIST 0                    // u32[8192]    32768
#define WS_META 32768                // u32[16]      64   [0]=M [1]=thr [2]=cum [3]=coarseN
#define WS_SUP  32832                // u64[64]      512   (supany bitmask)
#define WS_VALM 33344                // u64[64]      512   (valid bitmask)
#define WS_CKEY 33856                // u64[CAP]     262144 -> 296000  (packed s1|~idx)
#define WS_SEL  296000               // u32[TOPK]    16000  -> 312000
#define WS_NX1  312000               // f32[TOPK] each
#define WS_NY1  328000
#define WS_NX2  344000
#define WS_NY2  360000
#define WS_NAR  376000
#define WS_VAL  392000               // u32[TOPK] -> 408000
#define WS_MASK 408000               // u64[TOPK*64] = 2048000 -> 2456000
#define WS_RANK WS_MASK              // u32[CAP] alias (used before k_mask)
#define WS_COARSE (WS_MASK + 131072) // u64[CAP] alias (used before k_mask)
#define WS_DIAG 2456000              // u64[TOPK]    32000 -> 2488000
#define ZERO_A ((33856)/4)           // hist+meta+sup+valm in u32
#define ZERO_B (CAP)                 // rankbuf u32[CAP]

// d-bits bucket: d < -2 only; larger bucket == more negative d == higher score.
__device__ __forceinline__ int dbucket(float d) {
    u32 bits = __float_as_uint(d);
    int sb = (int)(bits - 0xC0000000u);   // >=0 iff d <= -2
    int b = sb >> 12;
    return (b > (NBUCKET - 1)) ? (NBUCKET - 1) : b;
}

// exact f32 s1 for l1>l0, bit-identical to numpy softmax chain
__device__ __forceinline__ float score1(float d) {
    float e0 = (float)::exp((double)d);
    float den = e0 + 1.0f;
    return 1.0f / den;
}

// full softmax (both outputs), identical op order to ref
__device__ __forceinline__ void softmax2(float l0, float l1, float& s0, float& s1) {
    float m = fmaxf(l0, l1);
    float a0 = l0 - m;
    float a1 = l1 - m;
    float e0 = (float)::exp((double)a0);
    float e1 = (float)::exp((double)a1);
    float den = e0 + e1;
    s0 = e0 / den;
    s1 = e1 / den;
}

__global__ void k_zero(u32* ws32) {
    int t = blockIdx.x * blockDim.x + threadIdx.x;
    if (t < ZERO_A) ws32[t] = 0;
    else if (t < ZERO_A + ZERO_B) ws32[WS_RANK/4 + (t - ZERO_A)] = 0;
}

// histogram of d-buckets + coarse candidate staging (block-aggregated)
__global__ void k_hist(const float* __restrict__ obj, u32* __restrict__ hist,
                       u64* __restrict__ coarse, u32* __restrict__ meta) {
    __shared__ u32 lh[NBUCKET];
    __shared__ u64 stage[512];
    __shared__ u32 scnt, sbase;
    int tid = threadIdx.x;
    for (int b = tid; b < NBUCKET; b += 256) lh[b] = 0;
    if (tid == 0) scnt = 0;
    __syncthreads();
    const float2* o2 = (const float2*)obj;
    int base = blockIdx.x * (256 * 9);
#pragma unroll
    for (int k = 0; k < 9; ++k) {
        int a = base + k * 256 + tid;
        float2 v = o2[a];
        float d = v.x - v.y;
        if (d < -2.0f) {
            atomicAdd(&lh[dbucket(d)], 1u);
            if (d < COARSE_CUT) {
                u32 p = atomicAdd(&scnt, 1u);
                if (p < 512) stage[p] = ((u64)__float_as_uint(d) << 32) | (u32)a;
            }
        }
    }
    __syncthreads();
    for (int b = tid; b < NBUCKET; b += 256) {
        u32 c = lh[b];
        if (c) atomicAdd(&hist[b], c);
    }
    u32 cnt = scnt; if (cnt > 512u) cnt = 512u;
    if (tid == 0 && cnt) sbase = atomicAdd(&meta[3], cnt);
    __syncthreads();
    if (cnt)
        for (u32 t = tid; t < cnt; t += 256) {
            u32 pos = sbase + t;
            if (pos < CAP) coarse[pos] = stage[t];
        }
}

// threshold bucket: smallest B with count(bucket >= B) >= TOPK; -1 margin for s1 ties
__global__ void k_scan(const u32* __restrict__ hist, u32* __restrict__ meta) {
    __shared__ u32 ss[1024];
    int t = threadIdx.x;
    u32 local = 0;
#pragma unroll
    for (int j = 0; j < 8; ++j) local += hist[t*8 + j];
    ss[t] = local;
    __syncthreads();
    for (int off = 1; off < 1024; off <<= 1) {
        u32 v = (t + off < 1024) ? ss[t + off] : 0;
        __syncthreads();
        ss[t] += v;
        __syncthreads();
    }
    u32 S_t = ss[t];
    u32 S_next = (t < 1023) ? ss[t+1] : 0;
    if (S_t >= TOPK && S_next < TOPK) {
        u32 cum = S_next;
        int bsel = t*8;
        for (int b = t*8 + 7; b >= t*8; --b) {
            cum += hist[b];
            if (cum >= TOPK) { bsel = b; break; }
        }
        meta[1] = (u32)((bsel > 0) ? bsel - 1 : 0);
        meta[2] = cum;
    }
}

// compact passers into packed keys. Fast path: scan the coarse list only.
__global__ void k_compact(const float* __restrict__ obj, u32* __restrict__ meta,
                          const u64* __restrict__ coarse, u64* __restrict__ ckeyp) {
    __shared__ u64 stage[512];
    __shared__ u32 scnt, sbase;
    int tid = threadIdx.x;
    if (tid == 0) scnt = 0;
    __syncthreads();
    int thr = (int)meta[1];
    u32 coarseN = meta[3];
    bool fast = (coarseN < (u32)CAP) && (thr >= COARSE_BUK);
    if (fast) {
        for (u32 t = blockIdx.x * 256 + tid; t < coarseN; t += gridDim.x * 256) {
            u64 e = coarse[t];
            float d = __uint_as_float((u32)(e >> 32));
            if (dbucket(d) >= thr) {
                float s1 = score1(d);
                if (s1 > 0.5f) {
                    u32 bits = __float_as_uint(s1);
                    u32 p = atomicAdd(&scnt, 1u);
                    if (p < 512) stage[p] = ((u64)bits << 32) | (u32)(~(u32)(e & 0xFFFFFFFFull));
                }
            }
        }
        __syncthreads();
        u32 cnt = scnt; if (cnt > 512u) cnt = 512u;
        if (tid == 0 && cnt) sbase = atomicAdd(&meta[0], cnt);
        __syncthreads();
        if (cnt)
            for (u32 t = tid; t < cnt; t += 256) {
                u32 pos = sbase + t;
                if (pos < CAP) ckeyp[pos] = stage[t];
            }
    } else {
        // fallback: full scan (rare; correctness path)
        const float2* o2 = (const float2*)obj;
        int base = blockIdx.x * (256 * 9);
#pragma unroll
        for (int k = 0; k < 9; ++k) {
            int a = base + k * 256 + tid;
            float2 v = o2[a];
            float d = v.x - v.y;
            if (d < -2.0f && dbucket(d) >= thr) {
                float s1 = score1(d);
                if (s1 > 0.5f) {
                    u32 bits = __float_as_uint(s1);
                    u32 pos = atomicAdd(&meta[0], 1u);
                    if (pos < CAP) ckeyp[pos] = ((u64)bits << 32) | (u32)(~(u32)a);
                }
            }
        }
    }
}

#define RSL 1024
// partial rank: block (bx,by) counts candidates by*256.. against ref slice bx*1024..
__global__ void k_rank(const u32* __restrict__ meta, const u64* __restrict__ ckeyp,
                       u32* __restrict__ rankbuf) {
    __shared__ u64 lk[RSL];
    int tid = threadIdx.x;
    u32 Mu = meta[0];
    int M = (int)(Mu < (u32)CAP ? Mu : (u32)CAP);
    int c = blockIdx.y * 256 + tid;
    if (blockIdx.y * 256 >= M) return;
    bool act = (c < M);
    u64 mypk = act ? ckeyp[c] : 0ull;
    int cnt = 0;
    for (int t0 = blockIdx.x * RSL; t0 < M; t0 += gridDim.x * RSL) {
        __syncthreads();
        for (int j = tid; j < RSL; j += 256)
            lk[j] = (t0 + j < M) ? ckeyp[t0 + j] : 0ull;
        __syncthreads();
#pragma unroll 16
        for (int j = 0; j < RSL; ++j)
            cnt += (lk[j] > mypk) ? 1 : 0;
    }
    if (act && cnt) atomicAdd(&rankbuf[c], (u32)cnt);
}

__global__ void k_sel(const u32* __restrict__ meta, const u64* __restrict__ ckeyp,
                      const u32* __restrict__ rankbuf, u32* __restrict__ sel) {
    u32 Mu = meta[0];
    int M = (int)(Mu < (u32)CAP ? Mu : (u32)CAP);
    int c = blockIdx.x * 256 + threadIdx.x;
    if (c >= M) return;
    u32 r = rankbuf[c];
    if (r < TOPK) sel[r] = ~(u32)(ckeyp[c] & 0xFFFFFFFFull);
}

__global__ void k_gather(const float* __restrict__ obj, const float* __restrict__ reg,
                         const float* __restrict__ anch, const u32* __restrict__ sel,
                         float* __restrict__ out,
                         float* __restrict__ nx1, float* __restrict__ ny1,
                         float* __restrict__ nx2, float* __restrict__ ny2,
                         float* __restrict__ nar, u32* __restrict__ valid,
                         u64* __restrict__ valm) {
    int r = blockIdx.x * 256 + threadIdx.x;
    if (r >= TOPK) return;
    u32 i = sel[r];
    u32 p = i / 9u, k = i - p * 9u;
    float l0 = obj[(size_t)p*18 + 2*k];
    float l1 = obj[(size_t)p*18 + 2*k + 1];
    float s0, s1;
    softmax2(l0, l1, s0, s1);
    const float* rg = reg + (size_t)p*36 + 4*k;
    float t0 = rg[0], t1 = rg[1], t2 = rg[2], t3 = rg[3];
    const float* an = anch + (size_t)i*4;
    float a0 = an[0], a1 = an[1], a2 = an[2], a3 = an[3];
    float cx = a0 + a2/2.0f + t0*a2;
    float cy = a1 + a3/2.0f + t1*a3;
    float w = a2 * (float)::exp((double)t2);
    float h = a3 * (float)::exp((double)t3);
    float bx = cx - w/2.0f;
    float by = cy - h/2.0f;
    float x1 = fminf(fmaxf(bx, 0.0f), IMG_SZ);
    float y1 = fminf(fmaxf(by, 0.0f), IMG_SZ);
    float x2 = fminf(fmaxf(bx + w, 0.0f), IMG_SZ);
    float y2 = fminf(fmaxf(by + h, 0.0f), IMG_SZ);
    float bw = x2 - x1, bh = y2 - y1;
    out[4*r+0] = x1;
    out[4*r+1] = y1;
    out[4*r+2] = bw;
    out[4*r+3] = bh;
    out[16000 + 2*r]     = s0;
    out[16000 + 2*r + 1] = s1;
    nx1[r] = x1; ny1[r] = y1;
    nx2[r] = x1 + bw;
    ny2[r] = y1 + bh;
    nar[r] = bw * bh;
    u32 vld = (s1 > 0.5f) ? 1u : 0u;
    valid[r] = vld;
    u64 bm = __ballot(vld != 0u);
    if ((threadIdx.x & 63) == 0) valm[r >> 6] = bm;
}

__device__ __forceinline__ bool iou_gt(float x1a, float y1a, float x2a, float y2a, float aA,
                                       float x1b, float y1b, float x2b, float y2b, float aB) {
    float iw = fminf(x2a, x2b) - fmaxf(x1a, x1b);
    float ih = fminf(y2a, y2b) - fmaxf(y1a, y1b);
    iw = fmaxf(iw, 0.0f);
    ih = fmaxf(ih, 0.0f);
    float inter = iw * ih;
    float iou = inter / (aA + aB - inter + 1e-8f);
    return iou > 0.3f;
}

// full suppression bitmask + per-row "suppresses anyone" summary + diagonal word
__global__ void k_mask(const float* __restrict__ nx1, const float* __restrict__ ny1,
                       const float* __restrict__ nx2, const float* __restrict__ ny2,
                       const float* __restrict__ nar, u64* __restrict__ mask,
                       u64* __restrict__ diag, u64* __restrict__ supany) {
    __shared__ float cx1[64], cy1[64], cx2[64], cy2[64], car[64];
    int w = blockIdx.y;
    int j0 = w * 64;
    int tid = threadIdx.x;
    if (tid < 64) {
        int j = j0 + tid;
        bool v = j < TOPK;
        cx1[tid] = v ? nx1[j] : 1e9f;
        cy1[tid] = v ? ny1[j] : 1e9f;
        cx2[tid] = v ? nx2[j] : 1e9f;
        cy2[tid] = v ? ny2[j] : 1e9f;
        car[tid] = v ? nar[j] : 0.f;
    }
    __syncthreads();
    int i = blockIdx.x * 256 + tid;
    if (i >= TOPK) return;
    float x1 = nx1[i], y1 = ny1[i], x2 = nx2[i], y2 = ny2[i], ar = nar[i];
    u64 bits = 0;
#pragma unroll
    for (int b = 0; b < 64; ++b) {
        int j = j0 + b;
        if (j < TOPK && j > i &&
            iou_gt(x1, y1, x2, y2, ar, cx1[b], cy1[b], cx2[b], cy2[b], car[b]))
            bits |= (1ull << b);
    }
    mask[(size_t)i * 64 + w] = bits;
    if (w == (i >> 6)) diag[i] = bits;
    u64 anyb = __ballot(bits != 0ull);
    if ((tid & 63) == 0 && anyb) atomicOr(&supany[i >> 6], anyb);
}

// 512 threads: all waves preload suppressor rows + diag into LDS; wave 0 scans.
__global__ __launch_bounds__(512) void k_scan_nms(const u64* __restrict__ mask,
                                                  const u64* __restrict__ diag,
                                                  const u64* __restrict__ supany,
                                                  const u64* __restrict__ valm,
                                                  float* __restrict__ out) {
    __shared__ u64 dlds[NWORD * 64];     // 32256 B: diagonal words
    __shared__ u64 cache[RCACHE * 64];   // 114688 B: suppressor rows
    __shared__ u32 rowlist[RCACHE];
    __shared__ u32 nrows_s;
    __shared__ u64 keep_s[64];
    int tid = threadIdx.x;
    int wave = tid >> 6, lane = tid & 63;

    for (int t = tid; t < NWORD * 64; t += 512)
        dlds[t] = (t < TOPK) ? diag[t] : 0ull;

    int excl = 0;
    u64 sa = 0;
    if (wave == 0) {
        sa = supany[lane];
        int c = (int)__popcll(sa);
        int pfx = c;
        for (int off = 1; off < 64; off <<= 1) {
            int n = __shfl_up(pfx, off);
            if (lane >= off) pfx += n;
        }
        excl = pfx - c;
        int total = __shfl(pfx, 63);
        if (lane == 0) nrows_s = (u32)((total < RCACHE) ? total : RCACHE);
        int s = excl; u64 t = sa;
        while (t) {
            int b = (int)__builtin_ctzll(t); t &= t - 1;
            if (s < RCACHE) rowlist[s] = (u32)((lane << 6) | b);
            s++;
        }
    }
    __syncthreads();
    int R = (int)nrows_s;
    {
        const int TW = RCACHE * 64;
        for (int t0 = tid; t0 < TW; t0 += 512 * 8) {
            u64 v[8];
#pragma unroll
            for (int u = 0; u < 8; ++u) {
                int t = t0 + u * 512;
                int sl = t >> 6;
                int row = (t < TW && sl < R) ? (int)rowlist[sl] : 0;
                v[u] = (t < TW) ? mask[(size_t)row * 64 + (t & 63)] : 0ull;
            }
#pragma unroll
            for (int u = 0; u < 8; ++u) {
                int t = t0 + u * 512;
                if (t < TW) cache[t] = v[u];
            }
        }
    }
    __syncthreads();
    if (wave == 0) {
        u64 kw = valm[lane];
        u64 gm = __ballot((sa & kw) != 0ull);
        while (gm) {
            int g = (int)__builtin_ctzll(gm); gm &= gm - 1;
            u64 wg  = __shfl(kw, g);
            u64 sag = __shfl(sa, g);
            u64 supAlive = wg & sag;
            if (supAlive == 0ull) continue;
            int sbase = __shfl(excl, g);
            u64 dg = dlds[(g << 6) | lane];
            u64 am = wg, act = supAlive, keptSup = 0ull;
            while (act) {
                int s = (int)__builtin_ctzll(act);
                u64 sup = __shfl(dg, s);
                am &= ~sup;
                keptSup |= (1ull << s);
                act &= ~(1ull << s);
                act &= am;
            }
            u64 acc = 0, t = keptSup;
            while (t) {
                int s1b = (int)__builtin_ctzll(t); t &= t - 1;
                int sl1 = sbase + (int)__popcll(sag & ((1ull << s1b) - 1ull));
                if (t) {
                    int s2b = (int)__builtin_ctzll(t); t &= t - 1;
                    int sl2 = sbase + (int)__popcll(sag & ((1ull << s2b) - 1ull));
                    u64 ra = (sl1 < RCACHE) ? cache[(sl1 << 6) | lane]
                                            : mask[(size_t)((g << 6) | s1b) * 64 + lane];
                    u64 rb = (sl2 < RCACHE) ? cache[(sl2 << 6) | lane]
                                            : mask[(size_t)((g << 6) | s2b) * 64 + lane];
                    acc |= ra | rb;
                } else {
                    acc |= (sl1 < RCACHE) ? cache[(sl1 << 6) | lane]
                                          : mask[(size_t)((g << 6) | s1b) * 64 + lane];
                }
            }
            kw &= ~acc;
        }
        keep_s[lane] = kw;
    }
    __syncthreads();
    for (int t = tid; t < TOPK; t += 512)
        out[24000 + t] = ((keep_s[t >> 6] >> (t & 63)) & 1ull) ? 1.0f : 0.0f;
}

extern "C" void kernel_launch(void* const* d_in, const int* in_sizes, int n_in,
                              void* d_out, int out_size, void* d_ws, size_t ws_size,
                              hipStream_t stream) {
    const float* obj  = (const float*)d_in[0];
    const float* reg  = (const float*)d_in[1];
    const float* anch = (const float*)d_in[2];
    float* out = (float*)d_out;
    char* ws = (char*)d_ws;

    u32* hist = (u32*)(ws + WS_HIST);
    u32* meta = (u32*)(ws + WS_META);
    u64* supany = (u64*)(ws + WS_SUP);
    u64* valm = (u64*)(ws + WS_VALM);
    u64* ckeyp = (u64*)(ws + WS_CKEY);
    u32* sel  = (u32*)(ws + WS_SEL);
    float* nx1 = (float*)(ws + WS_NX1);
    float* ny1 = (float*)(ws + WS_NY1);
    float* nx2 = (float*)(ws + WS_NX2);
    float* ny2 = (float*)(ws + WS_NY2);
    float* nar = (float*)(ws + WS_NAR);
    u32* valid = (u32*)(ws + WS_VAL);
    u64* mask  = (u64*)(ws + WS_MASK);
    u64* diag  = (u64*)(ws + WS_DIAG);
    u32* rankbuf = (u32*)(ws + WS_RANK);
    u64* coarse  = (u64*)(ws + WS_COARSE);

    hipLaunchKernelGGL(k_zero, dim3((ZERO_A + ZERO_B + 255) / 256), dim3(256), 0, stream, (u32*)ws);
    hipLaunchKernelGGL(k_hist, dim3(NANCH / (256*9)), dim3(256), 0, stream, obj, hist, coarse, meta);
    hipLaunchKernelGGL(k_scan, dim3(1), dim3(1024), 0, stream, hist, meta);
    hipLaunchKernelGGL(k_compact, dim3(NANCH / (256*9)), dim3(256), 0, stream, obj, meta, coarse, ckeyp);
    hipLaunchKernelGGL(k_rank, dim3(4, CAP/256), dim3(256), 0, stream, meta, ckeyp, rankbuf);
    hipLaunchKernelGGL(k_sel, dim3(CAP/256), dim3(256), 0, stream, meta, ckeyp, rankbuf, sel);
    hipLaunchKernelGGL(k_gather, dim3((TOPK + 255) / 256), dim3(256), 0, stream,
                       obj, reg, anch, sel, out, nx1, ny1, nx2, ny2, nar, valid, valm);
    hipLaunchKernelGGL(k_mask, dim3((TOPK + 255) / 256, 64), dim3(256), 0, stream,
                       nx1, ny1, nx2, ny2, nar, mask, diag, supany);
    hipLaunchKernelGGL(k_scan_nms, dim3(1), dim3(512), 0, stream, mask, diag, supany, valm, out);
}